// Round 3
// baseline (862.044 us; speedup 1.0000x reference)
//
#include <hip/hip_runtime.h>

namespace {

constexpr int N_NODES = 2048;
constexpr int IN_DIM  = 256;
constexpr int HEADS   = 6;
constexpr int HD      = 64;
constexpr int OUT_DIM = HEADS * HD;   // 384

// ---------------------------------------------------------------------------
// Kernel 1: projections + attention-vector dots, one block per (node, head, mat).
//   z=0: Q[head][i][f] = sum_k h[i,k] W_src[head][k][f];  qa = 0.6 * sum_f a_f Q_f
//   z=1: same with W_dst -> K, ka.
// block = 64 threads (one wave), f = threadIdx.x.
// ---------------------------------------------------------------------------
__global__ __launch_bounds__(64) void qk_proj(
    const float* __restrict__ hmat, const float* __restrict__ Wsrc,
    const float* __restrict__ Wdst, const float* __restrict__ a,
    float* __restrict__ Qw, float* __restrict__ Kw,
    float* __restrict__ qaw, float* __restrict__ kaw)
{
  const int f    = threadIdx.x;     // 0..63
  const int i    = blockIdx.x;      // node
  const int head = blockIdx.y;
  const int z    = blockIdx.z;      // 0 = src/Q, 1 = dst/K
  const float* __restrict__ W = (z ? Wdst : Wsrc) + (size_t)head * IN_DIM * HD;
  const float* __restrict__ hrow = hmat + (size_t)i * IN_DIM;

  float a0 = 0.f, a1 = 0.f, a2 = 0.f, a3 = 0.f;
  #pragma unroll 4
  for (int k = 0; k < IN_DIM; k += 4) {
    a0 = fmaf(hrow[k + 0], W[(k + 0) * HD + f], a0);
    a1 = fmaf(hrow[k + 1], W[(k + 1) * HD + f], a1);
    a2 = fmaf(hrow[k + 2], W[(k + 2) * HD + f], a2);
    a3 = fmaf(hrow[k + 3], W[(k + 3) * HD + f], a3);
  }
  const float acc = (a0 + a1) + (a2 + a3);
  (z ? Kw : Qw)[((size_t)head * N_NODES + i) * HD + f] = acc;

  float rsum = acc * a[head * HD + f];
  #pragma unroll
  for (int off = 32; off; off >>= 1) rsum += __shfl_xor(rsum, off);
  if (f == 0) (z ? kaw : qaw)[head * N_NODES + i] = 0.6f * rsum;
}

// ---------------------------------------------------------------------------
// Kernel 2: fused scores + masked softmax + attn_mean + PV + h'.
// grid 256 blocks x 256 threads; block owns 8 rows (i0..i0+7).
// SINGLE thread decomposition everywhere: r = t>>5 (row), jj = t&31.
//   pass 1 : per head, per j-tile of 128: stage K tile; each thread computes
//            e for its 4 j's (jj+32k) into e_lds[r][j]; running row-max.
//   reduce : 5-step shfl_xor max within the row's 32 lanes.
//   pass 2a: exp(e-m) back into e_lds (own slots) + row sum + shfl reduce.
//   pass 2b: per j-tile: restage K; attn_mean RMW on global (own slots);
//            PV: thread accumulates f = 2jj, 2jj+1 over all 128 j in-thread.
// e = 0.6*(a.Q_i) + 0.6*(a.K_j) + sum_f 0.4*a_f*|Q_if + K_jf|   (LeakyReLU 0.2)
// ---------------------------------------------------------------------------
__global__ __launch_bounds__(256, 1) void gat_fused(
    const float* __restrict__ Qw, const float* __restrict__ Kw,
    const float* __restrict__ qaw, const float* __restrict__ kaw,
    const float* __restrict__ a, const float* __restrict__ adj,
    const float* __restrict__ bias, float* __restrict__ out_h,
    float* __restrict__ out_attn)
{
  __shared__ float e_lds[8][N_NODES];   // 64 KB
  __shared__ float Kt[128][65];         // 33.3 KB, stride 65: conflict-free
  __shared__ float Qs[8][64];           // 2 KB
  __shared__ float a04[64];             // 0.25 KB

  const int t  = threadIdx.x;
  const int r  = t >> 5;                // row 0..7
  const int jj = t & 31;                // lane-in-row
  const int i0 = blockIdx.x * 8;

  for (int hh = 0; hh < HEADS; ++hh) {
    __syncthreads();   // previous head fully done with Qs/a04/Kt/e_lds
    for (int idx = t; idx < 512; idx += 256)
      Qs[idx >> 6][idx & 63] =
          Qw[((size_t)hh * N_NODES + i0 + (idx >> 6)) * HD + (idx & 63)];
    if (t < 64) a04[t] = 0.4f * a[hh * HD + t];
    __syncthreads();

    const float qa_r = qaw[hh * N_NODES + i0 + r];

    // ---------------- pass 1: e + running row max ----------------
    float m = -1e30f;
    for (int jt = 0; jt < 16; ++jt) {
      const int j0 = jt << 7;
      __syncthreads();                       // prior eacc reads of Kt done
      #pragma unroll
      for (int q = 0; q < 8; ++q) {          // stage K tile [128][64]
        const int f4 = t + (q << 8);
        const int row = f4 >> 4, c = (f4 & 15) << 2;
        const float4 v = *(const float4*)&Kw[((size_t)hh * N_NODES + j0 + row) * HD + c];
        Kt[row][c] = v.x; Kt[row][c + 1] = v.y; Kt[row][c + 2] = v.z; Kt[row][c + 3] = v.w;
      }
      __syncthreads();
      #pragma unroll
      for (int k = 0; k < 4; ++k) {
        const int j  = jj + (k << 5);
        const int jg = j0 + j;
        float A = 0.f;
        #pragma unroll
        for (int f0 = 0; f0 < 64; f0 += 4) {
          const float4 av = *(const float4*)&a04[f0];
          const float4 qv = *(const float4*)&Qs[r][f0];
          A = fmaf(fabsf(qv.x + Kt[j][f0 + 0]), av.x, A);
          A = fmaf(fabsf(qv.y + Kt[j][f0 + 1]), av.y, A);
          A = fmaf(fabsf(qv.z + Kt[j][f0 + 2]), av.z, A);
          A = fmaf(fabsf(qv.w + Kt[j][f0 + 3]), av.w, A);
        }
        const float ad  = adj[(size_t)(i0 + r) * N_NODES + jg];
        const float kaj = kaw[hh * N_NODES + jg];
        const float e = (ad > 0.f) ? (A + qa_r + kaj) : -1e30f;
        e_lds[r][jg] = e;
        m = fmaxf(m, e);
      }
    }
    #pragma unroll
    for (int off = 16; off; off >>= 1) m = fmaxf(m, __shfl_xor(m, off));

    // ---------------- pass 2a: exp + row sum (own slots only) ----------------
    float s0 = 0.f, s1 = 0.f, s2 = 0.f, s3 = 0.f;
    for (int jt = 0; jt < 16; ++jt) {
      const int j0 = jt << 7;
      const float v0 = __expf(e_lds[r][j0 + jj +  0] - m);
      const float v1 = __expf(e_lds[r][j0 + jj + 32] - m);
      const float v2 = __expf(e_lds[r][j0 + jj + 64] - m);
      const float v3 = __expf(e_lds[r][j0 + jj + 96] - m);
      e_lds[r][j0 + jj +  0] = v0;
      e_lds[r][j0 + jj + 32] = v1;
      e_lds[r][j0 + jj + 64] = v2;
      e_lds[r][j0 + jj + 96] = v3;
      s0 += v0; s1 += v1; s2 += v2; s3 += v3;
    }
    float s = (s0 + s1) + (s2 + s3);
    #pragma unroll
    for (int off = 16; off; off >>= 1) s += __shfl_xor(s, off);
    const float inv_s = 1.0f / s;
    __syncthreads();   // exp-values visible row-wide; Kt free for restage

    // ---------------- pass 2b: attn RMW + PV ----------------
    const int f0 = jj << 1, f1 = f0 + 1;
    float pv0a = 0.f, pv0b = 0.f, pv1a = 0.f, pv1b = 0.f;
    for (int jt = 0; jt < 16; ++jt) {
      const int j0 = jt << 7;
      #pragma unroll
      for (int q = 0; q < 8; ++q) {          // restage K tile
        const int f4 = t + (q << 8);
        const int row = f4 >> 4, c = (f4 & 15) << 2;
        const float4 v = *(const float4*)&Kw[((size_t)hh * N_NODES + j0 + row) * HD + c];
        Kt[row][c] = v.x; Kt[row][c + 1] = v.y; Kt[row][c + 2] = v.z; Kt[row][c + 3] = v.w;
      }
      // attn_mean accumulate on global (own slots; rows are block-exclusive)
      #pragma unroll
      for (int k = 0; k < 4; ++k) {
        const int jg = j0 + jj + (k << 5);
        const float p = e_lds[r][jg] * inv_s;
        const size_t ai = (size_t)(i0 + r) * N_NODES + jg;
        if (hh == 0)               out_attn[ai] = p;
        else if (hh == HEADS - 1)  out_attn[ai] = (out_attn[ai] + p) * (1.0f / 6.0f);
        else                       out_attn[ai] += p;
      }
      __syncthreads();                       // Kt staged before PV reads
      #pragma unroll 4
      for (int j2 = 0; j2 < 128; j2 += 2) {  // 4 independent fma chains
        const float va = e_lds[r][j0 + j2];
        const float vb = e_lds[r][j0 + j2 + 1];
        pv0a = fmaf(va, Kt[j2][f0],     pv0a);
        pv1a = fmaf(va, Kt[j2][f1],     pv1a);
        pv0b = fmaf(vb, Kt[j2 + 1][f0], pv0b);
        pv1b = fmaf(vb, Kt[j2 + 1][f1], pv1b);
      }
      __syncthreads();                       // PV reads done before next restage
    }
    out_h[(size_t)(i0 + r) * OUT_DIM + hh * HD + f0] =
        (pv0a + pv0b) * inv_s + bias[hh * HD + f0];
    out_h[(size_t)(i0 + r) * OUT_DIM + hh * HD + f1] =
        (pv1a + pv1b) * inv_s + bias[hh * HD + f1];
  }
}

}  // namespace

// ---------------------------------------------------------------------------
extern "C" void kernel_launch(void* const* d_in, const int* in_sizes, int n_in,
                              void* d_out, int out_size, void* d_ws, size_t ws_size,
                              hipStream_t stream) {
  const float* hmat = (const float*)d_in[0];
  const float* adj  = (const float*)d_in[1];
  const float* Wsrc = (const float*)d_in[2];
  const float* Wdst = (const float*)d_in[3];
  const float* a    = (const float*)d_in[4];
  const float* bias = (const float*)d_in[5];

  float* out_h    = (float*)d_out;                        // 2048 x 384
  float* out_attn = out_h + (size_t)N_NODES * OUT_DIM;    // 2048 x 2048

  float* Qw  = (float*)d_ws;                              // [6][2048][64]
  float* Kw  = Qw + (size_t)HEADS * N_NODES * HD;         // [6][2048][64]
  float* qaw = Kw + (size_t)HEADS * N_NODES * HD;         // [6][2048]
  float* kaw = qaw + HEADS * N_NODES;                     // [6][2048]

  qk_proj<<<dim3(N_NODES, HEADS, 2), 64, 0, stream>>>(hmat, Wsrc, Wdst, a,
                                                      Qw, Kw, qaw, kaw);
  gat_fused<<<dim3(N_NODES / 8), 256, 0, stream>>>(Qw, Kw, qaw, kaw, a, adj,
                                                   bias, out_h, out_attn);
}